// Round 4
// baseline (29419.360 us; speedup 1.0000x reference)
//
#include <hip/hip_runtime.h>

#define TT 512
#define BB 64
#define II 1024
#define HH 1024
#define GG 4096   /* 4*H */
#define BH 65536  /* B*H */
#define NBLK 256

typedef __attribute__((ext_vector_type(8))) short bf16x8;
typedef __attribute__((ext_vector_type(4))) float f32x4;

__device__ unsigned int g_bar_count = 0;
__device__ unsigned int g_bar_sense = 0;

__device__ __forceinline__ float bf2f(unsigned short u) {
  union { unsigned int i; float f; } v; v.i = ((unsigned int)u) << 16; return v.f;
}
__device__ __forceinline__ unsigned short f2bf(float f) {
  union { float f; unsigned int i; } v; v.f = f;
  return (unsigned short)((v.i + 0x7FFFu + ((v.i >> 16) & 1u)) >> 16);
}
__device__ __forceinline__ bf16x8 pack8(float4 a, float4 b) {
  union { bf16x8 v; unsigned short u[8]; } p;
  p.u[0] = f2bf(a.x); p.u[1] = f2bf(a.y); p.u[2] = f2bf(a.z); p.u[3] = f2bf(a.w);
  p.u[4] = f2bf(b.x); p.u[5] = f2bf(b.y); p.u[6] = f2bf(b.z); p.u[7] = f2bf(b.w);
  return p.v;
}
__device__ __forceinline__ float sigmoid_f(float x) { return 1.0f / (1.0f + __expf(-x)); }
__device__ __forceinline__ float tanh_f(float x) {
  float e = __expf(-2.0f * fabsf(x));
  float t = (1.0f - e) / (1.0f + e);
  return copysignf(t, x);
}

// sense-reversal grid barrier; NBLK blocks, call from all threads.
// count self-resets on completion; sense logic parity-agnostic -> graph-replay safe.
__device__ __forceinline__ void grid_barrier() {
  __threadfence();
  __syncthreads();
  if (threadIdx.x == 0) {
    unsigned s = __hip_atomic_load(&g_bar_sense, __ATOMIC_RELAXED, __HIP_MEMORY_SCOPE_AGENT);
    unsigned old = __hip_atomic_fetch_add(&g_bar_count, 1u, __ATOMIC_ACQ_REL, __HIP_MEMORY_SCOPE_AGENT);
    if (old == NBLK - 1u) {
      __hip_atomic_store(&g_bar_count, 0u, __ATOMIC_RELAXED, __HIP_MEMORY_SCOPE_AGENT);
      __hip_atomic_store(&g_bar_sense, s ^ 1u, __ATOMIC_RELEASE, __HIP_MEMORY_SCOPE_AGENT);
    } else {
      while (__hip_atomic_load(&g_bar_sense, __ATOMIC_ACQUIRE, __HIP_MEMORY_SCOPE_AGENT) == s) {
        __builtin_amdgcn_s_sleep(2);
      }
    }
  }
  __syncthreads();
}

// ---------------- input GEMM chunk ----------------
// gxc[m][n] = sum_k xc[m][k]*w_ih[n][k] + b_ih[n] + b_hh[n], m in [0, tc*64)
// grid = (Mc/128)*32 blocks; 128x128 tile, BK=64, 256 threads (4 waves, 64x64 each).
__global__ __launch_bounds__(256) void wdlstm_gemm_gx(
    const float* __restrict__ xc, const float* __restrict__ w_ih,
    const float* __restrict__ b_ih, const float* __restrict__ b_hh,
    unsigned short* __restrict__ gxc) {
  __shared__ __align__(16) char As[16384];  // [128][64] bf16, XOR-swizzled
  __shared__ __align__(16) char Bs[16384];

  const int tid = threadIdx.x;
  const int bx  = blockIdx.x;
  const int tm  = bx >> 5, tn = bx & 31;
  const int m0  = tm * 128, n0 = tn * 128;
  const int wv  = tid >> 6, l = tid & 63;
  const int wr  = wv >> 1, wc = wv & 1;
  const int ln  = l & 15, lq = l >> 4;

  f32x4 acc[4][4];
#pragma unroll
  for (int i = 0; i < 4; ++i)
#pragma unroll
    for (int j = 0; j < 4; ++j) acc[i][j] = (f32x4){0.f, 0.f, 0.f, 0.f};

  for (int kt = 0; kt < 16; ++kt) {
    const int k0 = kt * 64;
    __syncthreads();
#pragma unroll
    for (int o = 0; o < 4; ++o) {
      int c2 = tid + 256 * o;        // 1024 16B-chunks
      int row = c2 >> 3, q8 = c2 & 7;
      int addr = (row * 128 + q8 * 16) ^ ((row & 7) << 4);
      {
        const float* s = xc + (size_t)(m0 + row) * II + k0 + q8 * 8;
        float4 a0 = *(const float4*)s;
        float4 a1 = *(const float4*)(s + 4);
        *(bf16x8*)(As + addr) = pack8(a0, a1);
      }
      {
        const float* s = w_ih + (size_t)(n0 + row) * II + k0 + q8 * 8;
        float4 a0 = *(const float4*)s;
        float4 a1 = *(const float4*)(s + 4);
        *(bf16x8*)(Bs + addr) = pack8(a0, a1);
      }
    }
    __syncthreads();
#pragma unroll
    for (int kc = 0; kc < 2; ++kc) {
      bf16x8 af[4], bfr[4];
#pragma unroll
      for (int mi = 0; mi < 4; ++mi) {
        int row = 64 * wr + 16 * mi + ln;
        int addr = (row * 128 + kc * 64 + lq * 16) ^ ((row & 7) << 4);
        af[mi] = *(const bf16x8*)(As + addr);
      }
#pragma unroll
      for (int ni = 0; ni < 4; ++ni) {
        int row = 64 * wc + 16 * ni + ln;
        int addr = (row * 128 + kc * 64 + lq * 16) ^ ((row & 7) << 4);
        bfr[ni] = *(const bf16x8*)(Bs + addr);
      }
#pragma unroll
      for (int mi = 0; mi < 4; ++mi)
#pragma unroll
        for (int ni = 0; ni < 4; ++ni)
          acc[mi][ni] = __builtin_amdgcn_mfma_f32_16x16x32_bf16(af[mi], bfr[ni], acc[mi][ni], 0, 0, 0);
    }
  }
  // epilogue: D[row=4*lq+r][col=ln] per 16x16 tile
#pragma unroll
  for (int mi = 0; mi < 4; ++mi)
#pragma unroll
    for (int ni = 0; ni < 4; ++ni) {
      int col = n0 + 64 * wc + 16 * ni + ln;
      float bv = b_ih[col] + b_hh[col];
#pragma unroll
      for (int r = 0; r < 4; ++r) {
        int row = m0 + 64 * wr + 16 * mi + 4 * lq + r;
        gxc[(size_t)row * GG + col] = f2bf(acc[mi][ni][r] + bv);
      }
    }
}

// ---------------- recurrence over one time-chunk [t0, t0+tc) ----------------
// 256 WGs x 256 threads. WG owns h-cols j0..j0+3 (16 gate cols: g*H + j0 + jj).
// Masked W slice (16x1024 bf16) in LDS for the whole chunk. c in a register
// (persisted via c_state). h broadcast via bf16 ping-pong hbuf; f32 h to d_out.
__global__ __launch_bounds__(256) void wdlstm_recurrence(
    const float* __restrict__ w_hh, const float* __restrict__ hh_mask,
    const unsigned short* __restrict__ gxc,
    float* __restrict__ out, float* __restrict__ c_state,
    unsigned short* __restrict__ hbuf,   // [2][BH] bf16 ping-pong
    int t0, int tc) {
  __shared__ __align__(16) char Wlds[32768];     // [16][1024] bf16, XOR-swizzled
  __shared__ float Dlds[4][16 * 17];             // per-wave 16x16 f32, pad 17

  const int tid = threadIdx.x;
  const int wv  = tid >> 6, l = tid & 63;
  const int ln  = l & 15, lq = l >> 4;
  const int j0  = blockIdx.x * 4;

  // preload masked W slice: LDS row n (0..15) = w_hh row (n>>2)*H + j0 + (n&3)
#pragma unroll
  for (int c8 = 0; c8 < 8; ++c8) {
    int c = tid + 256 * c8;          // 2048 chunks of 8 elems
    int n = c >> 7, cc = c & 127;
    int wrow = (n >> 2) * HH + j0 + (n & 3);
    const float* sw = w_hh   + (size_t)wrow * HH + cc * 8;
    const float* sm = hh_mask + (size_t)wrow * HH + cc * 8;
    float4 w0 = *(const float4*)sw, w1 = *(const float4*)(sw + 4);
    float4 m0 = *(const float4*)sm, m1 = *(const float4*)(sm + 4);
    float4 p0 = {w0.x * m0.x, w0.y * m0.y, w0.z * m0.z, w0.w * m0.w};
    float4 p1 = {w1.x * m1.x, w1.y * m1.y, w1.z * m1.z, w1.w * m1.w};
    int addr = (n * 2048 + cc * 16) ^ ((n & 7) << 4);
    *(bf16x8*)(Wlds + addr) = pack8(p0, p1);
  }
  __syncthreads();

  // lane owns state for (b = 16*wv + ln, j = j0 + lq)
  const int b_ep = 16 * wv + ln;
  const int j_ep = j0 + lq;
  float c_reg = (t0 == 0) ? 0.0f : c_state[b_ep * HH + j_ep];

  float* hn_out = out + (size_t)TT * BH;
  float* cn_out = hn_out + BH;

  // prefetch gx for lt=0
  float gxv[4];
  {
    const unsigned short* gp = gxc + (size_t)b_ep * GG + j_ep;
#pragma unroll
    for (int g = 0; g < 4; ++g) gxv[g] = bf2f(gp[g * HH]);
  }

  for (int lt = 0; lt < tc; ++lt) {
    const int t = t0 + lt;
    const unsigned short* hb_prev = hbuf + (size_t)((t ^ 1) & 1) * BH;
    unsigned short*       hb_cur  = hbuf + (size_t)(t & 1) * BH;

    // ---- recurrent GEMM: D = h_prev @ W_slice^T (16x16 per wave, K=1024); h(-1)=0 -> D=0
    f32x4 acc = (f32x4){0.f, 0.f, 0.f, 0.f};
    if (t > 0) {
      const unsigned short* ap = hb_prev + (size_t)(16 * wv + ln) * HH + lq * 8;
#pragma unroll 8
      for (int kc = 0; kc < 32; ++kc) {
        bf16x8 a = *(const bf16x8*)(ap + kc * 32);
        int baddr = (ln * 2048 + kc * 64 + lq * 16) ^ ((ln & 7) << 4);
        bf16x8 b = *(const bf16x8*)(Wlds + baddr);
        acc = __builtin_amdgcn_mfma_f32_16x16x32_bf16(a, b, acc, 0, 0, 0);
      }
    }
    // transpose D through LDS: D[row=4*lq+r][col=ln]
#pragma unroll
    for (int r = 0; r < 4; ++r)
      Dlds[wv][(4 * lq + r) * 17 + ln] = acc[r];
    __syncthreads();

    // ---- elementwise: lane handles (b_ep, j_ep); slice gate col = g*4 + lq
    float g0 = Dlds[wv][ln * 17 + 0  + lq] + gxv[0];
    float g1 = Dlds[wv][ln * 17 + 4  + lq] + gxv[1];
    float g2 = Dlds[wv][ln * 17 + 8  + lq] + gxv[2];
    float g3 = Dlds[wv][ln * 17 + 12 + lq] + gxv[3];
    float ig = sigmoid_f(g0);
    float fg = sigmoid_f(g1);
    float gg = tanh_f(g2);
    float og = sigmoid_f(g3);
    c_reg = fg * c_reg + ig * gg;
    float h = og * tanh_f(c_reg);
    out[(size_t)t * BH + b_ep * HH + j_ep] = h;          // f32 output
    hb_cur[b_ep * HH + j_ep] = f2bf(h);                  // bf16 broadcast for next step
    if (t == TT - 1) {
      hn_out[b_ep * HH + j_ep] = h;
      cn_out[b_ep * HH + j_ep] = c_reg;
    }

    // prefetch next step's gx (overlaps barrier wait)
    if (lt + 1 < tc) {
      const unsigned short* gp = gxc + ((size_t)(lt + 1) * BB + b_ep) * GG + j_ep;
#pragma unroll
      for (int g = 0; g < 4; ++g) gxv[g] = bf2f(gp[g * HH]);
      grid_barrier();
    }
  }

  // persist c across chunk launches
  c_state[b_ep * HH + j_ep] = c_reg;
}

extern "C" void kernel_launch(void* const* d_in, const int* in_sizes, int n_in,
                              void* d_out, int out_size, void* d_ws, size_t ws_size,
                              hipStream_t stream) {
  const float* x       = (const float*)d_in[0];
  const float* w_ih    = (const float*)d_in[1];
  const float* w_hh    = (const float*)d_in[2];
  const float* b_ih    = (const float*)d_in[3];
  const float* b_hh    = (const float*)d_in[4];
  const float* hh_mask = (const float*)d_in[5];
  float* out           = (float*)d_out;

  char* ws = (char*)d_ws;
  float* c_state       = (float*)ws;                          // 262144 B
  unsigned short* hbuf = (unsigned short*)(ws + 262144);      // 2*131072 B
  unsigned short* gxc  = (unsigned short*)(ws + 524288);      // chunk buffer

  // adaptive time-chunk: fit chunk gx (TC*B*4H*2 B) in remaining ws, cap at 128 steps
  const size_t per_t = (size_t)BB * GG * 2;                   // 524288 B per step
  long long avail = (ws_size > 524288) ? (long long)(ws_size - 524288) : 0;
  int TC = (int)(avail / (long long)per_t);
  if (TC > 128) TC = 128;
  TC &= ~1;                   // keep chunk-M a multiple of 128
  if (TC < 2) TC = 2;         // last resort

  for (int t0 = 0; t0 < TT; t0 += TC) {
    int tc = TT - t0 < TC ? TT - t0 : TC;
    const float* xc = x + (size_t)t0 * BB * II;
    int grid = (tc * 64 / 128) * 32;
    wdlstm_gemm_gx<<<grid, 256, 0, stream>>>(xc, w_ih, b_ih, b_hh, gxc);
    wdlstm_recurrence<<<NBLK, 256, 0, stream>>>(w_hh, hh_mask, gxc, out, c_state, hbuf, t0, tc);
  }
}

// Round 5
// 7142.125 us; speedup vs baseline: 4.1191x; 4.1191x over previous
//
#include <hip/hip_runtime.h>

#define TT 512
#define BB 64
#define II 1024
#define HH 1024
#define GG 4096   /* 4*H */
#define BH 65536  /* B*H */
#define NBLK 256

typedef __attribute__((ext_vector_type(8))) short bf16x8;
typedef __attribute__((ext_vector_type(4))) float f32x4;

// flag-array sense barrier state (zero-initialized .bss; parity restored every replay)
__device__ unsigned g_sense2;
__device__ unsigned g_flags[NBLK * 16];   // one 64B line per block

__device__ __forceinline__ float bf2f(unsigned short u) {
  union { unsigned int i; float f; } v; v.i = ((unsigned int)u) << 16; return v.f;
}
__device__ __forceinline__ unsigned short f2bf(float f) {
  union { float f; unsigned int i; } v; v.f = f;
  return (unsigned short)((v.i + 0x7FFFu + ((v.i >> 16) & 1u)) >> 16);
}
__device__ __forceinline__ bf16x8 pack8(float4 a, float4 b) {
  union { bf16x8 v; unsigned short u[8]; } p;
  p.u[0] = f2bf(a.x); p.u[1] = f2bf(a.y); p.u[2] = f2bf(a.z); p.u[3] = f2bf(a.w);
  p.u[4] = f2bf(b.x); p.u[5] = f2bf(b.y); p.u[6] = f2bf(b.z); p.u[7] = f2bf(b.w);
  return p.v;
}
__device__ __forceinline__ float sigmoid_f(float x) { return 1.0f / (1.0f + __expf(-x)); }
__device__ __forceinline__ float tanh_f(float x) {
  float e = __expf(-2.0f * fabsf(x));
  float t = (1.0f - e) / (1.0f + e);
  return copysignf(t, x);
}

__device__ __forceinline__ unsigned ld_rlx(const unsigned* p) {
  return __hip_atomic_load(p, __ATOMIC_RELAXED, __HIP_MEMORY_SCOPE_AGENT);
}
__device__ __forceinline__ unsigned ld_acq(const unsigned* p) {
  return __hip_atomic_load(p, __ATOMIC_ACQUIRE, __HIP_MEMORY_SCOPE_AGENT);
}

// Flag-array sense-reversal grid barrier. No atomic RMW: arrivals are parallel
// release-stores to per-block 64B-padded flags; block 0's 256 threads poll one
// flag each (relaxed + periodic acquire for progress), then release g_sense2.
// Invariant: on entry all flags == tgt^1; on exit all == tgt.
__device__ __forceinline__ void grid_barrier2(unsigned tgt) {
  __syncthreads();   // block's h-stores issued & acked (compiler drains vmcnt before s_barrier)
  const int tid = threadIdx.x;
  if (tid == 0)
    __hip_atomic_store(&g_flags[blockIdx.x * 16], tgt, __ATOMIC_RELEASE, __HIP_MEMORY_SCOPE_AGENT);
  if (blockIdx.x == 0) {
    // each thread polls one block's flag; parallel detection
    const unsigned* fp = &g_flags[tid * 16];
    int it = 0;
    while (ld_rlx(fp) != tgt) {
      if ((++it & 31) == 0) { if (ld_acq(fp) == tgt) break; }
      __builtin_amdgcn_s_sleep(1);
    }
    __syncthreads();                     // all 256 flags observed
    if (tid == 0)
      __hip_atomic_store(&g_sense2, tgt, __ATOMIC_RELEASE, __HIP_MEMORY_SCOPE_AGENT);
  } else {
    if (tid == 0) {
      const unsigned* sp = &g_sense2;
      int it = 0;
      while (ld_rlx(sp) != tgt) {
        if ((++it & 31) == 0) { if (ld_acq(sp) == tgt) break; }
        __builtin_amdgcn_s_sleep(1);
      }
    }
    __syncthreads();
  }
  if (tid == 0) __builtin_amdgcn_fence(__ATOMIC_ACQUIRE, "agent");  // one inv covers the CU
  __syncthreads();
}

// ---------------- input GEMM chunk ----------------
// gxc[m][n] = sum_k xc[m][k]*w_ih[n][k] + b_ih[n] + b_hh[n], m in [0, tc*64)
__global__ __launch_bounds__(256) void wdlstm_gemm_gx(
    const float* __restrict__ xc, const float* __restrict__ w_ih,
    const float* __restrict__ b_ih, const float* __restrict__ b_hh,
    unsigned short* __restrict__ gxc) {
  __shared__ __align__(16) char As[16384];  // [128][64] bf16, XOR-swizzled
  __shared__ __align__(16) char Bs[16384];

  const int tid = threadIdx.x;
  const int bx  = blockIdx.x;
  const int tm  = bx >> 5, tn = bx & 31;
  const int m0  = tm * 128, n0 = tn * 128;
  const int wv  = tid >> 6, l = tid & 63;
  const int wr  = wv >> 1, wc = wv & 1;
  const int ln  = l & 15, lq = l >> 4;

  f32x4 acc[4][4];
#pragma unroll
  for (int i = 0; i < 4; ++i)
#pragma unroll
    for (int j = 0; j < 4; ++j) acc[i][j] = (f32x4){0.f, 0.f, 0.f, 0.f};

  for (int kt = 0; kt < 16; ++kt) {
    const int k0 = kt * 64;
    __syncthreads();
#pragma unroll
    for (int o = 0; o < 4; ++o) {
      int c2 = tid + 256 * o;        // 1024 16B-chunks
      int row = c2 >> 3, q8 = c2 & 7;
      int addr = (row * 128 + q8 * 16) ^ ((row & 7) << 4);
      {
        const float* s = xc + (size_t)(m0 + row) * II + k0 + q8 * 8;
        float4 a0 = *(const float4*)s;
        float4 a1 = *(const float4*)(s + 4);
        *(bf16x8*)(As + addr) = pack8(a0, a1);
      }
      {
        const float* s = w_ih + (size_t)(n0 + row) * II + k0 + q8 * 8;
        float4 a0 = *(const float4*)s;
        float4 a1 = *(const float4*)(s + 4);
        *(bf16x8*)(Bs + addr) = pack8(a0, a1);
      }
    }
    __syncthreads();
#pragma unroll
    for (int kc = 0; kc < 2; ++kc) {
      bf16x8 af[4], bfr[4];
#pragma unroll
      for (int mi = 0; mi < 4; ++mi) {
        int row = 64 * wr + 16 * mi + ln;
        int addr = (row * 128 + kc * 64 + lq * 16) ^ ((row & 7) << 4);
        af[mi] = *(const bf16x8*)(As + addr);
      }
#pragma unroll
      for (int ni = 0; ni < 4; ++ni) {
        int row = 64 * wc + 16 * ni + ln;
        int addr = (row * 128 + kc * 64 + lq * 16) ^ ((row & 7) << 4);
        bfr[ni] = *(const bf16x8*)(Bs + addr);
      }
#pragma unroll
      for (int mi = 0; mi < 4; ++mi)
#pragma unroll
        for (int ni = 0; ni < 4; ++ni)
          acc[mi][ni] = __builtin_amdgcn_mfma_f32_16x16x32_bf16(af[mi], bfr[ni], acc[mi][ni], 0, 0, 0);
    }
  }
#pragma unroll
  for (int mi = 0; mi < 4; ++mi)
#pragma unroll
    for (int ni = 0; ni < 4; ++ni) {
      int col = n0 + 64 * wc + 16 * ni + ln;
      float bv = b_ih[col] + b_hh[col];
#pragma unroll
      for (int r = 0; r < 4; ++r) {
        int row = m0 + 64 * wr + 16 * mi + 4 * lq + r;
        gxc[(size_t)row * GG + col] = f2bf(acc[mi][ni][r] + bv);
      }
    }
}

// ---------------- recurrence over one time-chunk [t0, t0+tc) ----------------
__global__ __launch_bounds__(256) void wdlstm_recurrence(
    const float* __restrict__ w_hh, const float* __restrict__ hh_mask,
    const unsigned short* __restrict__ gxc,
    float* __restrict__ out, float* __restrict__ c_state,
    unsigned short* __restrict__ hbuf,   // [2][BH] bf16 ping-pong
    int t0, int tc, unsigned sense0, int tail_bar) {
  __shared__ __align__(16) char Wlds[32768];     // [16][1024] bf16, XOR-swizzled
  __shared__ float Dlds[4][16 * 17];             // per-wave 16x16 f32, pad 17

  const int tid = threadIdx.x;
  const int wv  = tid >> 6, l = tid & 63;
  const int ln  = l & 15, lq = l >> 4;
  const int j0  = blockIdx.x * 4;

  // preload masked W slice: LDS row n (0..15) = w_hh row (n>>2)*H + j0 + (n&3)
#pragma unroll
  for (int c8 = 0; c8 < 8; ++c8) {
    int c = tid + 256 * c8;          // 2048 chunks of 8 elems
    int n = c >> 7, cc = c & 127;
    int wrow = (n >> 2) * HH + j0 + (n & 3);
    const float* sw = w_hh   + (size_t)wrow * HH + cc * 8;
    const float* sm = hh_mask + (size_t)wrow * HH + cc * 8;
    float4 w0 = *(const float4*)sw, w1 = *(const float4*)(sw + 4);
    float4 m0 = *(const float4*)sm, m1 = *(const float4*)(sm + 4);
    float4 p0 = {w0.x * m0.x, w0.y * m0.y, w0.z * m0.z, w0.w * m0.w};
    float4 p1 = {w1.x * m1.x, w1.y * m1.y, w1.z * m1.z, w1.w * m1.w};
    int addr = (n * 2048 + cc * 16) ^ ((n & 7) << 4);
    *(bf16x8*)(Wlds + addr) = pack8(p0, p1);
  }
  __syncthreads();

  // lane owns state for (b = 16*wv + ln, j = j0 + lq)
  const int b_ep = 16 * wv + ln;
  const int j_ep = j0 + lq;
  float c_reg = (t0 == 0) ? 0.0f : c_state[b_ep * HH + j_ep];
  unsigned cur = sense0;

  float* hn_out = out + (size_t)TT * BH;
  float* cn_out = hn_out + BH;

  // prefetch gx for lt=0
  float gxv[4];
  {
    const unsigned short* gp = gxc + (size_t)b_ep * GG + j_ep;
#pragma unroll
    for (int g = 0; g < 4; ++g) gxv[g] = bf2f(gp[g * HH]);
  }

  for (int lt = 0; lt < tc; ++lt) {
    const int t = t0 + lt;
    const unsigned short* hb_prev = hbuf + (size_t)((t ^ 1) & 1) * BH;
    unsigned short*       hb_cur  = hbuf + (size_t)(t & 1) * BH;

    // ---- recurrent GEMM: D = h_prev @ W_slice^T (16x16 per wave, K=1024); h(-1)=0 -> D=0
    f32x4 acc = (f32x4){0.f, 0.f, 0.f, 0.f};
    if (t > 0) {
      const unsigned short* ap = hb_prev + (size_t)(16 * wv + ln) * HH + lq * 8;
#pragma unroll 8
      for (int kc = 0; kc < 32; ++kc) {
        bf16x8 a = *(const bf16x8*)(ap + kc * 32);
        int baddr = (ln * 2048 + kc * 64 + lq * 16) ^ ((ln & 7) << 4);
        bf16x8 b = *(const bf16x8*)(Wlds + baddr);
        acc = __builtin_amdgcn_mfma_f32_16x16x32_bf16(a, b, acc, 0, 0, 0);
      }
    }
    // transpose D through LDS: D[row=4*lq+r][col=ln]
#pragma unroll
    for (int r = 0; r < 4; ++r)
      Dlds[wv][(4 * lq + r) * 17 + ln] = acc[r];
    __syncthreads();

    // ---- elementwise: lane handles (b_ep, j_ep); slice gate col = g*4 + lq
    float g0 = Dlds[wv][ln * 17 + 0  + lq] + gxv[0];
    float g1 = Dlds[wv][ln * 17 + 4  + lq] + gxv[1];
    float g2 = Dlds[wv][ln * 17 + 8  + lq] + gxv[2];
    float g3 = Dlds[wv][ln * 17 + 12 + lq] + gxv[3];
    float ig = sigmoid_f(g0);
    float fg = sigmoid_f(g1);
    float gg = tanh_f(g2);
    float og = sigmoid_f(g3);
    c_reg = fg * c_reg + ig * gg;
    float h = og * tanh_f(c_reg);
    out[(size_t)t * BH + b_ep * HH + j_ep] = h;          // f32 output
    hb_cur[b_ep * HH + j_ep] = f2bf(h);                  // bf16 broadcast for next step
    if (t == TT - 1) {
      hn_out[b_ep * HH + j_ep] = h;
      cn_out[b_ep * HH + j_ep] = c_reg;
    }

    // prefetch next step's gx into registers (survives the barrier), then sync
    if (lt + 1 < tc) {
      const unsigned short* gp = gxc + ((size_t)(lt + 1) * BB + b_ep) * GG + j_ep;
#pragma unroll
      for (int g = 0; g < 4; ++g) gxv[g] = bf2f(gp[g * HH]);
      cur ^= 1u;
      grid_barrier2(cur);
    }
  }

  // persist c across chunk launches
  c_state[b_ep * HH + j_ep] = c_reg;

  // parity-restoring dummy barrier (keeps global flag state replay-invariant)
  if (tail_bar) { cur ^= 1u; grid_barrier2(cur); }
}

extern "C" void kernel_launch(void* const* d_in, const int* in_sizes, int n_in,
                              void* d_out, int out_size, void* d_ws, size_t ws_size,
                              hipStream_t stream) {
  const float* x       = (const float*)d_in[0];
  const float* w_ih    = (const float*)d_in[1];
  const float* w_hh    = (const float*)d_in[2];
  const float* b_ih    = (const float*)d_in[3];
  const float* b_hh    = (const float*)d_in[4];
  const float* hh_mask = (const float*)d_in[5];
  float* out           = (float*)d_out;

  char* ws = (char*)d_ws;
  float* c_state       = (float*)ws;                          // 262144 B
  unsigned short* hbuf = (unsigned short*)(ws + 262144);      // 2*131072 B
  unsigned short* gxc  = (unsigned short*)(ws + 524288);      // chunk buffer

  // adaptive time-chunk: fit chunk gx (TC*B*4H*2 B) in remaining ws, cap at 128 steps
  const size_t per_t = (size_t)BB * GG * 2;                   // 524288 B per step
  long long avail = (ws_size > 524288) ? (long long)(ws_size - 524288) : 0;
  int TC = (int)(avail / (long long)per_t);
  if (TC > 128) TC = 128;
  TC &= ~1;
  if (TC < 2) TC = 2;

  // precompute chunk boundaries + barrier parity; ensure total barrier count even
  unsigned parity = 0;
  int nbar_total = 0;
  for (int t0 = 0; t0 < TT; t0 += TC) {
    int tc = TT - t0 < TC ? TT - t0 : TC;
    nbar_total += tc - 1;
  }
  int need_tail = nbar_total & 1;

  for (int t0 = 0; t0 < TT; t0 += TC) {
    int tc = TT - t0 < TC ? TT - t0 : TC;
    int is_last = (t0 + tc >= TT);
    const float* xc = x + (size_t)t0 * BB * II;
    int grid = (tc * 64 / 128) * 32;
    wdlstm_gemm_gx<<<grid, 256, 0, stream>>>(xc, w_ih, b_ih, b_hh, gxc);
    int tail = is_last ? need_tail : 0;
    wdlstm_recurrence<<<NBLK, 256, 0, stream>>>(w_hh, hh_mask, gxc, out, c_state, hbuf,
                                                t0, tc, parity, tail);
    parity ^= (unsigned)((tc - 1 + tail) & 1);
  }
}